// Round 1
// baseline (213.901 us; speedup 1.0000x reference)
//
#include <hip/hip_runtime.h>

#define BSZ 4
#define SEQ 4096
#define DIM 1024
#define MD 64
#define NT 1
#define TOPK 16

// One 256-thread block per (batch, seq) row. Each thread owns 4 contiguous
// elements (float4 coalesced). Key identity: with only the first 64 FWHT
// outputs kept, the 1024-pt transform reduces to a 64-bin fold
// (bin = inv_perm[d] & 63) followed by a 64-pt Hadamard. Wave 0 does both
// 64-pt Hadamards via shuffle-xor butterflies entirely in registers.
__global__ __launch_bounds__(256) void csa_kernel(
    const float* __restrict__ x,
    const float* __restrict__ gates,
    const float* __restrict__ alpha,
    const float* __restrict__ tau,
    const float* __restrict__ signs,
    const int*   __restrict__ inv_perm,
    const int*   __restrict__ target_idx,
    float*       __restrict__ out)
{
    __shared__ float s_bins[MD];
    __shared__ float s_w[MD];

    const int row = blockIdx.x;          // 0 .. BSZ*SEQ-1
    const int b   = row >> 12;           // SEQ = 4096
    const int t   = threadIdx.x;

    if (t < MD) s_bins[t] = 0.0f;
    __syncthreads();

    // Coalesced float4 loads; keep x in registers for the final add.
    const float4 xv = ((const float4*)(x + (size_t)row * DIM))[t];
    const float4 sg = ((const float4*)signs)[t];
    const int4   ip = ((const int4*)inv_perm)[t];

    // Fold x*signs into 64 bins: s[m] = sum over d with inv_perm[d]&63 == m.
    atomicAdd(&s_bins[ip.x & (MD - 1)], xv.x * sg.x);
    atomicAdd(&s_bins[ip.y & (MD - 1)], xv.y * sg.y);
    atomicAdd(&s_bins[ip.z & (MD - 1)], xv.z * sg.z);
    atomicAdd(&s_bins[ip.w & (MD - 1)], xv.w * sg.w);

    __syncthreads();

    if (t < MD) {   // wave 0 only (64 lanes)
        // 64-pt Hadamard of s_bins (xor butterflies; stage order commutes).
        float v = s_bins[t];
        #pragma unroll
        for (int bit = 1; bit < MD; bit <<= 1) {
            float o = __shfl_xor(v, bit, MD);
            v = (t & bit) ? (o - v) : (v + o);
        }
        const int   ti   = target_idx[0];               // always 0 here
        const float gate = gates[(b * NT + ti) * MD + t];
        const float g    = gate * v * 0.03125f;          // 1024^-0.5
        const float ag   = fabsf(g);

        // Exact top-16 rank: count lanes strictly better; ties -> lower index.
        int cnt = 0;
        #pragma unroll
        for (int j = 0; j < MD; ++j) {
            const float aj = __shfl(ag, j, MD);
            cnt += (aj > ag) || (aj == ag && j < t);
        }
        const float tauv = fabsf(tau[b * NT + ti]);
        const float al   = alpha[b * NT + ti];
        float zs = (cnt < TOPK && ag >= tauv) ? (al * g) : 0.0f;

        // Second 64-pt Hadamard.
        #pragma unroll
        for (int bit = 1; bit < MD; bit <<= 1) {
            float o = __shfl_xor(zs, bit, MD);
            zs = (t & bit) ? (o - zs) : (zs + o);
        }
        s_w[t] = zs * 0.03125f;                          // 1024^-0.5
    }
    __syncthreads();

    float4 ov;
    ov.x = xv.x + sg.x * s_w[ip.x & (MD - 1)];
    ov.y = xv.y + sg.y * s_w[ip.y & (MD - 1)];
    ov.z = xv.z + sg.z * s_w[ip.z & (MD - 1)];
    ov.w = xv.w + sg.w * s_w[ip.w & (MD - 1)];
    ((float4*)(out + (size_t)row * DIM))[t] = ov;
}

extern "C" void kernel_launch(void* const* d_in, const int* in_sizes, int n_in,
                              void* d_out, int out_size, void* d_ws, size_t ws_size,
                              hipStream_t stream) {
    const float* x        = (const float*)d_in[0];
    const float* gates    = (const float*)d_in[1];
    const float* alpha    = (const float*)d_in[2];
    const float* tau      = (const float*)d_in[3];
    const float* signs    = (const float*)d_in[4];
    // d_in[5] = perm (unused; inv_perm suffices)
    const int*   inv_perm = (const int*)d_in[6];
    const int*   tgt      = (const int*)d_in[7];
    float*       out      = (float*)d_out;

    csa_kernel<<<BSZ * SEQ, 256, 0, stream>>>(x, gates, alpha, tau, signs,
                                              inv_perm, tgt, out);
}

// Round 2
// 127.483 us; speedup vs baseline: 1.6779x; 1.6779x over previous
//
#include <hip/hip_runtime.h>

#define SEQ 4096
#define DIM 1024
#define MD 64
#define TOPK 16
#define RPB 4   // rows (waves) per block

// One WAVE per row: no atomics, no __syncthreads, no idle waves.
// Identities used (validated in round 1):
//   z_m  = 1024^-0.5 * H64( s )_m, where s[m] = sum_k x[perm[m+64k]]*signs[perm[m+64k]]
//   r_d  = 1024^-0.5 * H64( zs )_{inv_perm[d]&63} * signs[d]
// (inv_perm is a permutation, so bin m's members are exactly perm[m+64k], k=0..15)
__global__ __launch_bounds__(256) void csa_kernel(
    const float* __restrict__ x,
    const float* __restrict__ gates,
    const float* __restrict__ alpha,
    const float* __restrict__ tau,
    const float* __restrict__ signs,
    const int*   __restrict__ perm,
    const int*   __restrict__ inv_perm,
    const int*   __restrict__ target_idx,
    float*       __restrict__ out)
{
    __shared__ float y[RPB][DIM];   // per-wave staging of x*signs (16 KB/block)

    const int t    = threadIdx.x;
    const int lane = t & 63;
    const int wv   = t >> 6;
    const int row  = (blockIdx.x << 2) | wv;   // 0 .. BSZ*SEQ-1
    const int b    = row >> 12;                // SEQ = 4096

    const float* xr = x + (size_t)row * DIM;

    // ---- Phase 1: coalesced load, stage y = x*signs into this wave's LDS row
    #pragma unroll
    for (int c = 0; c < 4; ++c) {
        const float4 xv = ((const float4*)xr)[c * 64 + lane];
        const float4 sg = ((const float4*)signs)[c * 64 + lane];
        float4 yv;
        yv.x = xv.x * sg.x; yv.y = xv.y * sg.y;
        yv.z = xv.z * sg.z; yv.w = xv.w * sg.w;
        ((float4*)y[wv])[c * 64 + lane] = yv;
    }

    // ---- Phase 2: fold 1024 -> 64 bins, lane m owns bin m (gather, no atomics)
    int pidx[16];
    #pragma unroll
    for (int k = 0; k < 16; ++k) pidx[k] = perm[lane + 64 * k];  // coalesced, L1-hot
    float s = 0.f;
    #pragma unroll
    for (int k = 0; k < 16; ++k) s += y[wv][pidx[k]];

    // ---- Phase 3a: 64-pt Hadamard in registers (shuffle-xor butterflies)
    float v = s;
    #pragma unroll
    for (int bit = 1; bit < MD; bit <<= 1) {
        const float o = __shfl_xor(v, bit, MD);
        v = (lane & bit) ? (o - v) : (v + o);
    }

    const int   ti   = target_idx[0];                    // NT == 1
    const float gate = gates[(b + ti) * MD + lane];
    const float g    = gate * v * 0.03125f;              // 1024^-0.5
    const float ag   = fabsf(g);

    // ---- Phase 3b: exact top-16 via bitwise binary search on |g| bits.
    // T converges to the 16th-largest key; ties broken by lowest lane index
    // (matches jax.lax.top_k) via prefix-popcount over the equal mask.
    const unsigned ka = __float_as_uint(ag);             // ag >= 0: bits are order-preserving
    unsigned T = 0u;
    #pragma unroll
    for (int bit = 30; bit >= 0; --bit) {
        const unsigned cand = T | (1u << bit);
        if (__popcll(__ballot(ka >= cand)) >= TOPK) T = cand;
    }
    const int ngt = __popcll(__ballot(ka > T));
    const unsigned long long eq = __ballot(ka == T);
    const int eqrank = __popcll(eq & ((1ull << lane) - 1ull));
    const bool keep = (ka > T) || ((ka == T) && (eqrank < TOPK - ngt));

    const float tauv = fabsf(tau[b + ti]);
    const float al   = alpha[b + ti];
    float zs = (keep && ag >= tauv) ? al * g : 0.f;

    // ---- Phase 3c: second 64-pt Hadamard
    #pragma unroll
    for (int bit = 1; bit < MD; bit <<= 1) {
        const float o = __shfl_xor(zs, bit, MD);
        zs = (lane & bit) ? (o - zs) : (zs + o);
    }
    const float w = zs * 0.03125f;                       // 1024^-0.5
    const int   wbits = __float_as_int(w);

    // ---- Phase 4: out[d] = signs[d] * (y[d] + w[inv_perm[d]&63])
    float* outr = out + (size_t)row * DIM;
    #pragma unroll
    for (int c = 0; c < 4; ++c) {
        const float4 yv = ((const float4*)y[wv])[c * 64 + lane];
        const float4 sg = ((const float4*)signs)[c * 64 + lane];
        const int4   ip = ((const int4*)inv_perm)[c * 64 + lane];
        float4 ov;
        ov.x = sg.x * (yv.x + __int_as_float(__builtin_amdgcn_ds_bpermute((ip.x & 63) << 2, wbits)));
        ov.y = sg.y * (yv.y + __int_as_float(__builtin_amdgcn_ds_bpermute((ip.y & 63) << 2, wbits)));
        ov.z = sg.z * (yv.z + __int_as_float(__builtin_amdgcn_ds_bpermute((ip.z & 63) << 2, wbits)));
        ov.w = sg.w * (yv.w + __int_as_float(__builtin_amdgcn_ds_bpermute((ip.w & 63) << 2, wbits)));
        ((float4*)outr)[c * 64 + lane] = ov;
    }
}

extern "C" void kernel_launch(void* const* d_in, const int* in_sizes, int n_in,
                              void* d_out, int out_size, void* d_ws, size_t ws_size,
                              hipStream_t stream) {
    const float* x        = (const float*)d_in[0];
    const float* gates    = (const float*)d_in[1];
    const float* alpha    = (const float*)d_in[2];
    const float* tau      = (const float*)d_in[3];
    const float* signs    = (const float*)d_in[4];
    const int*   perm     = (const int*)d_in[5];
    const int*   inv_perm = (const int*)d_in[6];
    const int*   tgt      = (const int*)d_in[7];
    float*       out      = (float*)d_out;

    const int rows = (4 * SEQ);                  // BSZ * SEQ
    csa_kernel<<<rows / RPB, 256, 0, stream>>>(x, gates, alpha, tau, signs,
                                               perm, inv_perm, tgt, out);
}

// Round 3
// 127.272 us; speedup vs baseline: 1.6807x; 1.0017x over previous
//
#include <hip/hip_runtime.h>

#define SEQ 4096
#define DIM 1024
#define MD 64
#define TOPK 16
#define WPB 2                 // waves per block
#define RPW 2                 // rows per wave (ILP: two independent chains)
#define RPB (WPB * RPW)       // 4 rows per block, 16 KB LDS

// One wave processes TWO rows with all phases pairwise interleaved.
// Identities (validated R1/R2):
//   z_m = 1024^-0.5 * H64(s)_m,  s[m] = sum_k y[perm[m+64k]],  y = x*signs
//   out = signs * (y + 1024^-0.5 * H64(zs)[inv_perm & 63])
// Rows (2m, 2m+1) always share the same batch index b (pair never straddles
// a multiple of SEQ since pair starts are even).
__global__ __launch_bounds__(WPB * 64) void csa_kernel(
    const float* __restrict__ x,
    const float* __restrict__ gates,
    const float* __restrict__ alpha,
    const float* __restrict__ tau,
    const float* __restrict__ signs,
    const int*   __restrict__ perm,
    const int*   __restrict__ inv_perm,
    const int*   __restrict__ target_idx,
    float*       __restrict__ out)
{
    __shared__ float y[RPB][DIM];

    const int lane = threadIdx.x & 63;
    const int wv   = threadIdx.x >> 6;
    const int r0   = (blockIdx.x * WPB + wv) * RPW;   // first of 2 rows
    const int b    = r0 >> 12;                        // SEQ = 4096

    // ---- Phase 1: coalesced load x for both rows, stage y = x*signs to LDS
    #pragma unroll
    for (int c = 0; c < 4; ++c) {
        const float4 sg = ((const float4*)signs)[c * 64 + lane];
        #pragma unroll
        for (int r = 0; r < RPW; ++r) {
            const float4 xv = ((const float4*)(x + (size_t)(r0 + r) * DIM))[c * 64 + lane];
            float4 yv;
            yv.x = xv.x * sg.x; yv.y = xv.y * sg.y;
            yv.z = xv.z * sg.z; yv.w = xv.w * sg.w;
            ((float4*)y[wv * RPW + r])[c * 64 + lane] = yv;
        }
    }

    // ---- Phase 2: fold 1024 -> 64 bins; lane m owns bin m, both rows share perm
    float s0 = 0.f, s1 = 0.f;
    #pragma unroll
    for (int k = 0; k < 16; ++k) {
        const int p = perm[lane + 64 * k];            // L1-hot, shared
        s0 += y[wv * RPW + 0][p];
        s1 += y[wv * RPW + 1][p];
    }

    // ---- Phase 3a: 64-pt Hadamard, both rows interleaved
    float v0 = s0, v1 = s1;
    #pragma unroll
    for (int bit = 1; bit < MD; bit <<= 1) {
        const float o0 = __shfl_xor(v0, bit, 64);
        const float o1 = __shfl_xor(v1, bit, 64);
        v0 = (lane & bit) ? (o0 - v0) : (v0 + o0);
        v1 = (lane & bit) ? (o1 - v1) : (v1 + o1);
    }

    const int   ti   = target_idx[0];                 // NT == 1
    const float gate = gates[(b + ti) * MD + lane];
    const float tauv = fabsf(tau[b + ti]);
    const float al   = alpha[b + ti];

    const float g0 = gate * v0 * 0.03125f;            // 1024^-0.5
    const float g1 = gate * v1 * 0.03125f;
    const float ag0 = fabsf(g0), ag1 = fabsf(g1);

    // ---- Phase 3b: exact top-16 threshold via bitwise binary search (2 chains)
    const unsigned ka0 = __float_as_uint(ag0);
    const unsigned ka1 = __float_as_uint(ag1);
    unsigned T0 = 0u, T1 = 0u;
    #pragma unroll
    for (int bit = 30; bit >= 0; --bit) {
        const unsigned c0 = T0 | (1u << bit);
        const unsigned c1 = T1 | (1u << bit);
        if (__popcll(__ballot(ka0 >= c0)) >= TOPK) T0 = c0;
        if (__popcll(__ballot(ka1 >= c1)) >= TOPK) T1 = c1;
    }
    const int ngt0 = __popcll(__ballot(ka0 > T0));
    const int ngt1 = __popcll(__ballot(ka1 > T1));
    const unsigned long long lm = (1ull << lane) - 1ull;
    const int er0 = __popcll(__ballot(ka0 == T0) & lm);
    const int er1 = __popcll(__ballot(ka1 == T1) & lm);
    const bool k0 = (ka0 > T0) || ((ka0 == T0) && (er0 < TOPK - ngt0));
    const bool k1 = (ka1 > T1) || ((ka1 == T1) && (er1 < TOPK - ngt1));

    float zs0 = (k0 && ag0 >= tauv) ? al * g0 : 0.f;
    float zs1 = (k1 && ag1 >= tauv) ? al * g1 : 0.f;

    // ---- Phase 3c: second 64-pt Hadamard, interleaved
    #pragma unroll
    for (int bit = 1; bit < MD; bit <<= 1) {
        const float o0 = __shfl_xor(zs0, bit, 64);
        const float o1 = __shfl_xor(zs1, bit, 64);
        zs0 = (lane & bit) ? (o0 - zs0) : (zs0 + o0);
        zs1 = (lane & bit) ? (o1 - zs1) : (zs1 + o1);
    }
    const int wb0 = __float_as_int(zs0 * 0.03125f);
    const int wb1 = __float_as_int(zs1 * 0.03125f);

    // ---- Phase 4: out = signs * (y + w[inv_perm & 63]), both rows
    float* out0 = out + (size_t)(r0 + 0) * DIM;
    float* out1 = out + (size_t)(r0 + 1) * DIM;
    #pragma unroll
    for (int c = 0; c < 4; ++c) {
        const float4 sg = ((const float4*)signs)[c * 64 + lane];
        const int4   ip = ((const int4*)inv_perm)[c * 64 + lane];
        const int a0 = (ip.x & 63) << 2, a1 = (ip.y & 63) << 2;
        const int a2 = (ip.z & 63) << 2, a3 = (ip.w & 63) << 2;

        const float4 y0 = ((const float4*)y[wv * RPW + 0])[c * 64 + lane];
        const float4 y1 = ((const float4*)y[wv * RPW + 1])[c * 64 + lane];

        float4 o0, o1;
        o0.x = sg.x * (y0.x + __int_as_float(__builtin_amdgcn_ds_bpermute(a0, wb0)));
        o0.y = sg.y * (y0.y + __int_as_float(__builtin_amdgcn_ds_bpermute(a1, wb0)));
        o0.z = sg.z * (y0.z + __int_as_float(__builtin_amdgcn_ds_bpermute(a2, wb0)));
        o0.w = sg.w * (y0.w + __int_as_float(__builtin_amdgcn_ds_bpermute(a3, wb0)));
        o1.x = sg.x * (y1.x + __int_as_float(__builtin_amdgcn_ds_bpermute(a0, wb1)));
        o1.y = sg.y * (y1.y + __int_as_float(__builtin_amdgcn_ds_bpermute(a1, wb1)));
        o1.z = sg.z * (y1.z + __int_as_float(__builtin_amdgcn_ds_bpermute(a2, wb1)));
        o1.w = sg.w * (y1.w + __int_as_float(__builtin_amdgcn_ds_bpermute(a3, wb1)));

        ((float4*)out0)[c * 64 + lane] = o0;
        ((float4*)out1)[c * 64 + lane] = o1;
    }
}

extern "C" void kernel_launch(void* const* d_in, const int* in_sizes, int n_in,
                              void* d_out, int out_size, void* d_ws, size_t ws_size,
                              hipStream_t stream) {
    const float* x        = (const float*)d_in[0];
    const float* gates    = (const float*)d_in[1];
    const float* alpha    = (const float*)d_in[2];
    const float* tau      = (const float*)d_in[3];
    const float* signs    = (const float*)d_in[4];
    const int*   perm     = (const int*)d_in[5];
    const int*   inv_perm = (const int*)d_in[6];
    const int*   tgt      = (const int*)d_in[7];
    float*       out      = (float*)d_out;

    const int rows = 4 * SEQ;                         // BSZ * SEQ
    csa_kernel<<<rows / RPB, WPB * 64, 0, stream>>>(x, gates, alpha, tau, signs,
                                                    perm, inv_perm, tgt, out);
}